// Round 1
// 279.073 us; speedup vs baseline: 1.0944x; 1.0944x over previous
//
#include <hip/hip_runtime.h>

// Problem constants (B=4, Hs=Ws=256, C=128, n_heads=4, head_dim=32)
#define HW 65536          // Hs*Ws positions per batch
#define CH 128
#define NHEADS 4
#define HDIM 32
#define EPS 1e-5f
#define INV_NP (1.0f / 65536.0f)
#define INV_C (1.0f / 128.0f)

typedef float v4f __attribute__((ext_vector_type(4)));
typedef short v8s __attribute__((ext_vector_type(8)));
typedef unsigned int v4u __attribute__((ext_vector_type(4)));

__device__ __forceinline__ ushort f2bf(float f) {
    uint u = __float_as_uint(f);
    return (ushort)((u + 0x7FFFu + ((u >> 16) & 1u)) >> 16);
}

// HW packed f32->bf16 (RTNE), 2 elements / instruction
__device__ __forceinline__ uint cvtpk(float lo, float hi) {
    uint r;
    asm("v_cvt_pk_bf16_f32 %0, %1, %2" : "=v"(r) : "v"(lo), "v"(hi));
    return r;
}

__device__ __forceinline__ v8s pack8(const float4& a, const float4& b) {
    union { uint u[4]; v8s s; } r;
    r.u[0] = cvtpk(a.x, a.y);
    r.u[1] = cvtpk(a.z, a.w);
    r.u[2] = cvtpk(b.x, b.y);
    r.u[3] = cvtpk(b.z, b.w);
    return r.s;
}

// DPP butterfly add-reduce across the 16 lanes of a DPP row (ln = lane&15).
// All lanes end with the sum. VALU-only: replaces 4-deep ds_swizzle chains.
template<int CTRL>
__device__ __forceinline__ float dppadd(float x) {
    return x + __int_as_float(
        __builtin_amdgcn_mov_dpp(__float_as_int(x), CTRL, 0xF, 0xF, true));
}
__device__ __forceinline__ float red16(float x) {
    x = dppadd<0xB1>(x);    // quad_perm [1,0,3,2]  (xor 1)
    x = dppadd<0x4E>(x);    // quad_perm [2,3,0,1]  (xor 2)
    x = dppadd<0x141>(x);   // row_half_mirror      (combine quads)
    x = dppadd<0x140>(x);   // row_mirror           (combine halves)
    return x;
}

#define MFMA(a, b, c) __builtin_amdgcn_mfma_f32_16x16x32_bf16((a), (b), (c), 0, 0, 0)

// Swizzled B-matrix image layout (bank-conflict-free MFMA B reads):
//   element (row j in 0..127, k in 0..127) stored at ushort index
//   j*128 + (((k>>3) + j) & 15)*8 + (k&7)
// Fragment read (row, kb=ks*4+q) => 16B at j*128 + ((kb+j)&15)*8.
// Since j&15 == ln, the slot index ((kb+j)&15) == ((ks*4+q+ln)&15): the
// whole address decomposes into loop-invariant row-base + ks-offset.

// ---------------------------------------------------------------------------
// prep: build swizzled bf16 WkT/WvT images; zero the kv accumulator.
// grid = 32, block = 256.
// ---------------------------------------------------------------------------
__global__ __launch_bounds__(256) void prep_kernel(const float* __restrict__ Wk,
                                                   const float* __restrict__ Wv,
                                                   ushort* __restrict__ SWkT,
                                                   ushort* __restrict__ SWvT,
                                                   float* __restrict__ kv_g) {
    const int t = blockIdx.x * 256 + threadIdx.x;   // 0..8191
    kv_g[t] = 0.f;
    kv_g[t + 8192] = 0.f;
#pragma unroll
    for (int i = 0; i < 2; ++i) {
        const int e = i * 8192 + t;          // e = c*128 + row
        const int c = e >> 7;
        const int row = e & 127;
        const int dst = row * 128 + (((c >> 3) + row) & 15) * 8 + (c & 7);
        SWkT[dst] = f2bf(Wk[e]);
        SWvT[dst] = f2bf(Wv[e]);
    }
}

// ---------------------------------------------------------------------------
// Kernel 1 (kv): each wave owns 16 positions and computes BOTH k and v for
// them (X loaded exactly once per block). Per 64-pos tile: prefetched X
// A-fragment (cvt_pk pack), 64 MFMAs (k+v), LN stats via DPP reduce,
// FMA-form normalize staged transposed (rotated layout), per-head kv
// outer-product MFMA in 2 rounds of 32 positions; atomicAdd at the end.
// LDS: SWkT[16384] @0, SWvT @16384, kst[4096] @32768, vst[4096] @36864 =80KB.
// grid = 512 (128/batch, 512 pos each), block = 256.
// ---------------------------------------------------------------------------
__global__ __launch_bounds__(256, 2) void kv_kernel(const float* __restrict__ X,
                                                    const ushort* __restrict__ SWkT,
                                                    const ushort* __restrict__ SWvT,
                                                    const float* __restrict__ gamma,
                                                    const float* __restrict__ beta,
                                                    float* __restrict__ kv_g) {
    __shared__ ushort lds[40960];
    const int tid  = threadIdx.x;
    const int lane = tid & 63;
    const int w    = tid >> 6;
    const int q    = lane >> 4;
    const int ln   = lane & 15;

    const int batch  = blockIdx.x >> 7;
    const int blocal = blockIdx.x & 127;
    const float* Xb = X + ((size_t)batch * HW + (size_t)blocal * 512) * CH;

    // linear (conflict-free) staging of the swizzled W images
    {
        const v4u* sk = (const v4u*)SWkT;
        const v4u* sv = (const v4u*)SWvT;
        v4u* dk = (v4u*)lds;
        v4u* dv = (v4u*)(lds + 16384);
#pragma unroll
        for (int n = 0; n < 8; ++n) {
            dk[n * 256 + tid] = sk[n * 256 + tid];
            dv[n * 256 + tid] = sv[n * 256 + tid];
        }
    }

    float g8[8], be8[8];
#pragma unroll
    for (int ct = 0; ct < 8; ++ct) {
        g8[ct]  = gamma[ct * 16 + ln];
        be8[ct] = beta[ct * 16 + ln];
    }

    // ---- loop-invariant LDS offsets (ushort units) ----
    int brow[8];                              // GEMM B row bases
#pragma unroll
    for (int ct = 0; ct < 8; ++ct) brow[ct] = (ct * 16 + ln) * 128;
    int bks[4];                               // GEMM B ks-slot offsets
#pragma unroll
    for (int ks = 0; ks < 4; ++ks) bks[ks] = ((ks * 4 + q + ln) & 15) * 8;
    int soff[8];                              // stage-write bases (per ct)
#pragma unroll
    for (int ct = 0; ct < 8; ++ct) {
        const int chn  = ct * 16 + ln;
        const int slot = (((w & 1) << 1) + (q >> 1) + chn) & 3;
        soff[ct] = chn * 32 + slot * 8 + (q & 1) * 4;
    }
    const int r0 = w * 32 + ln;               // kv-phase read rows (head = w)
    const int r1 = r0 + 16;
    const int koff0 = r0 * 32 + ((q + r0) & 3) * 8;
    const int koff1 = r1 * 32 + ((q + r1) & 3) * 8;

    v4f kv00 = {0.f, 0.f, 0.f, 0.f}, kv01 = kv00, kv10 = kv00, kv11 = kv00;

    // ---- prologue: load tile 0 (this wave's 16 rows, once) ----
    const float* xbase = Xb + (w * 16 + ln) * CH + q * 8;
    float4 xa[8];
#pragma unroll
    for (int ks = 0; ks < 4; ++ks) {
        xa[2 * ks]     = *(const float4*)(xbase + ks * 32);
        xa[2 * ks + 1] = *(const float4*)(xbase + ks * 32 + 4);
    }
    __syncthreads();                           // W images ready

    v8s A[4];
#pragma unroll
    for (int ks = 0; ks < 4; ++ks) A[ks] = pack8(xa[2 * ks], xa[2 * ks + 1]);

    for (int t = 0; t < 8; ++t) {
        // ---- prefetch next tile's X (latency hides under GEMM+LN) ----
        if (t < 7) {
            const float* xp = xbase + (size_t)(t + 1) * 64 * CH;
#pragma unroll
            for (int ks = 0; ks < 4; ++ks) {
                xa[2 * ks]     = *(const float4*)(xp + ks * 32);
                xa[2 * ks + 1] = *(const float4*)(xp + ks * 32 + 4);
            }
        }

        // ---- GEMM: 16 pos x 128 cols of k AND v ----
        v4f ak[8], av[8];
#pragma unroll
        for (int ct = 0; ct < 8; ++ct) {
            ak[ct] = (v4f){0.f, 0.f, 0.f, 0.f};
            av[ct] = (v4f){0.f, 0.f, 0.f, 0.f};
        }
#pragma unroll
        for (int ks = 0; ks < 4; ++ks) {
#pragma unroll
            for (int ct = 0; ct < 8; ++ct) {
                const int kb = brow[ct] + bks[ks];
                const v8s Bk = *(const v8s*)(lds + kb);
                const v8s Bv = *(const v8s*)(lds + 16384 + kb);
                ak[ct] = MFMA(A[ks], Bk, ak[ct]);
                av[ct] = MFMA(A[ks], Bv, av[ct]);
            }
        }

        // ---- LN stats (both tensors) via DPP butterfly ----
        float rsk[4], rsv[4], mrk[4], mrv[4];
#pragma unroll
        for (int r = 0; r < 4; ++r) {
            float sk = 0.f, qk = 0.f, sv = 0.f, qv = 0.f;
#pragma unroll
            for (int ct = 0; ct < 8; ++ct) {
                sk += ak[ct][r]; qk = fmaf(ak[ct][r], ak[ct][r], qk);
                sv += av[ct][r]; qv = fmaf(av[ct][r], av[ct][r], qv);
            }
            sk = red16(sk); qk = red16(qk);
            sv = red16(sv); qv = red16(qv);
            const float mk = sk * INV_C, mv = sv * INV_C;
            const float rk = __builtin_amdgcn_rsqf(fmaf(qk, INV_C, -mk * mk) + EPS);
            const float rv = __builtin_amdgcn_rsqf(fmaf(qv, INV_C, -mv * mv) + EPS);
            rsk[r] = rk; mrk[r] = mk * rk;
            rsv[r] = rv; mrv[r] = mv * rv;
        }

        // ---- two 32-pos rounds: stage normalized k,v transposed, MFMA outer
        // wave w stages its 16 positions in round (w>>1) at p32=(w&1)*16+q*4+r
#pragma unroll
        for (int rnd = 0; rnd < 2; ++rnd) {
            if ((w >> 1) == rnd) {
#pragma unroll
                for (int ct = 0; ct < 8; ++ct) {
#pragma unroll
                    for (int r = 0; r < 4; r += 2) {
                        const float k0 = fmaf(fmaf(ak[ct][r],     rsk[r],     -mrk[r]),     g8[ct], be8[ct]);
                        const float k1 = fmaf(fmaf(ak[ct][r + 1], rsk[r + 1], -mrk[r + 1]), g8[ct], be8[ct]);
                        const float v0 = fmaf(fmaf(av[ct][r],     rsv[r],     -mrv[r]),     g8[ct], be8[ct]);
                        const float v1 = fmaf(fmaf(av[ct][r + 1], rsv[r + 1], -mrv[r + 1]), g8[ct], be8[ct]);
                        *(uint*)(lds + 32768 + soff[ct] + r) = cvtpk(k0, k1);
                        *(uint*)(lds + 36864 + soff[ct] + r) = cvtpk(v0, v1);
                    }
                }
            }
            __syncthreads();
            {
                const v8s Ad0 = *(const v8s*)(lds + 32768 + koff0);
                const v8s Ad1 = *(const v8s*)(lds + 32768 + koff1);
                const v8s Be0 = *(const v8s*)(lds + 36864 + koff0);
                const v8s Be1 = *(const v8s*)(lds + 36864 + koff1);
                kv00 = MFMA(Ad0, Be0, kv00);
                kv01 = MFMA(Ad0, Be1, kv01);
                kv10 = MFMA(Ad1, Be0, kv10);
                kv11 = MFMA(Ad1, Be1, kv11);
            }
            __syncthreads();
        }

        // ---- pack prefetched tile into A-fragments ----
        if (t < 7) {
#pragma unroll
            for (int ks = 0; ks < 4; ++ks) A[ks] = pack8(xa[2 * ks], xa[2 * ks + 1]);
        }
    }

    float* dst = kv_g + (batch * NHEADS + w) * (HDIM * HDIM);
#pragma unroll
    for (int dt = 0; dt < 2; ++dt)
#pragma unroll
        for (int et = 0; et < 2; ++et) {
            const v4f f = dt == 0 ? (et == 0 ? kv00 : kv01) : (et == 0 ? kv10 : kv11);
#pragma unroll
            for (int r = 0; r < 4; ++r) {
                const int d = dt * 16 + q * 4 + r;
                const int e = et * 16 + ln;
                atomicAdd(&dst[d * HDIM + e], f[r]);
            }
        }
}

// ---------------------------------------------------------------------------
// Kernel 2: SWeffT = swizzled bf16 image of Weff^T where
// Weff[c][o] = (1/NP) sum_d Wq[c][h][d] kv[b][h][d][e], o = e*4+h.
// grid 64, block 256.
// ---------------------------------------------------------------------------
__global__ __launch_bounds__(256) void weff_kernel(const float* __restrict__ Wq,
                                                   const float* __restrict__ kv_g,
                                                   ushort* __restrict__ SWeffT) {
    const int b = blockIdx.x >> 4;
    const int part = blockIdx.x & 15;
    const int base = part * 1024 + threadIdx.x * 4;
    const int c = base >> 7;
    const int o0 = base & 127;
    const float* kvb = kv_g + b * (NHEADS * HDIM * HDIM);
#pragma unroll
    for (int n = 0; n < 4; ++n) {
        const int o = o0 + n;
        const int h = o & 3;
        const int e = o >> 2;
        float s = 0.f;
#pragma unroll
        for (int d = 0; d < HDIM; ++d)
            s += Wq[c * CH + h * HDIM + d] * kvb[h * (HDIM * HDIM) + d * HDIM + e];
        SWeffT[b * (CH * CH) + o * 128 + (((c >> 3) + o) & 15) * 8 + (c & 7)] = f2bf(s * INV_NP);
    }
}

// ---------------------------------------------------------------------------
// Kernel 3 (out): operand-swapped MFMA — A = Weff rows (from the swizzled
// LDS image, same addressing as a B-read), B = X positions. C rows are then
// OUTPUT CHANNELS -> each lane stores a float4 (8 dwordx4/tile vs 32 dwords).
// Each wave owns disjoint 16 positions (X read once per block), prefetched.
// grid = 1024 (256/batch, 4 tiles of 64 pos each), block = 256.
// ---------------------------------------------------------------------------
__global__ __launch_bounds__(256, 4) void out_kernel(const float* __restrict__ X,
                                                     const ushort* __restrict__ SWeffT,
                                                     float* __restrict__ out) {
    __shared__ ushort lds[16384];
    const int tid  = threadIdx.x;
    const int lane = tid & 63;
    const int w    = tid >> 6;
    const int q    = lane >> 4;
    const int ln   = lane & 15;

    const int batch  = blockIdx.x >> 8;
    const int blocal = blockIdx.x & 255;
    const size_t p0 = (size_t)batch * HW + (size_t)blocal * 256;

    {
        const v4u* s = (const v4u*)(SWeffT + batch * (CH * CH));
        v4u* d = (v4u*)lds;
#pragma unroll
        for (int n = 0; n < 8; ++n) d[n * 256 + tid] = s[n * 256 + tid];
    }

    int arow[8];
#pragma unroll
    for (int ot = 0; ot < 8; ++ot) arow[ot] = (ot * 16 + ln) * 128;
    int aks[4];
#pragma unroll
    for (int ks = 0; ks < 4; ++ks) aks[ks] = ((ks * 4 + q + ln) & 15) * 8;

    const float* xbase = X + (p0 + w * 16 + ln) * CH + q * 8;
    float* obase       = out + (p0 + w * 16 + ln) * CH + q * 4;

    float4 xa[8];
#pragma unroll
    for (int ks = 0; ks < 4; ++ks) {
        xa[2 * ks]     = *(const float4*)(xbase + ks * 32);
        xa[2 * ks + 1] = *(const float4*)(xbase + ks * 32 + 4);
    }
    __syncthreads();

    v8s Bx[4];
#pragma unroll
    for (int ks = 0; ks < 4; ++ks) Bx[ks] = pack8(xa[2 * ks], xa[2 * ks + 1]);

    for (int t = 0; t < 4; ++t) {
        if (t < 3) {
            const float* xp = xbase + (size_t)(t + 1) * 64 * CH;
#pragma unroll
            for (int ks = 0; ks < 4; ++ks) {
                xa[2 * ks]     = *(const float4*)(xp + ks * 32);
                xa[2 * ks + 1] = *(const float4*)(xp + ks * 32 + 4);
            }
        }

        v4f acc[8];
#pragma unroll
        for (int ot = 0; ot < 8; ++ot) acc[ot] = (v4f){0.f, 0.f, 0.f, 0.f};
#pragma unroll
        for (int ks = 0; ks < 4; ++ks) {
#pragma unroll
            for (int ot = 0; ot < 8; ++ot) {
                const v8s Aw = *(const v8s*)(lds + arow[ot] + aks[ks]);
                acc[ot] = MFMA(Aw, Bx[ks], acc[ot]);
            }
        }

        float* op = obase + (size_t)t * 64 * CH;
#pragma unroll
        for (int ot = 0; ot < 8; ++ot) {
            float4 s;
            s.x = acc[ot][0]; s.y = acc[ot][1]; s.z = acc[ot][2]; s.w = acc[ot][3];
            *(float4*)(op + ot * 16) = s;
        }

        if (t < 3) {
#pragma unroll
            for (int ks = 0; ks < 4; ++ks) Bx[ks] = pack8(xa[2 * ks], xa[2 * ks + 1]);
        }
    }
}

extern "C" void kernel_launch(void* const* d_in, const int* in_sizes, int n_in,
                              void* d_out, int out_size, void* d_ws, size_t ws_size,
                              hipStream_t stream) {
    const float* X     = (const float*)d_in[0];
    const float* Wq    = (const float*)d_in[1];
    const float* Wk    = (const float*)d_in[2];
    const float* Wv    = (const float*)d_in[3];
    const float* gamma = (const float*)d_in[4];
    const float* beta  = (const float*)d_in[5];
    float* out = (float*)d_out;

    float*  kv_g   = (float*)d_ws;                       // 64 KB
    ushort* SWkT   = (ushort*)((char*)d_ws + 65536);     // 32 KB
    ushort* SWvT   = (ushort*)((char*)d_ws + 98304);     // 32 KB
    ushort* SWeffT = (ushort*)((char*)d_ws + 131072);    // 128 KB

    prep_kernel<<<32, 256, 0, stream>>>(Wk, Wv, SWkT, SWvT, kv_g);
    kv_kernel<<<512, 256, 0, stream>>>(X, SWkT, SWvT, gamma, beta, kv_g);
    weff_kernel<<<64, 256, 0, stream>>>(Wq, kv_g, SWeffT);
    out_kernel<<<1024, 256, 0, stream>>>(X, SWeffT, out);
}

// Round 2
// 277.447 us; speedup vs baseline: 1.1008x; 1.0059x over previous
//
#include <hip/hip_runtime.h>

// Problem constants (B=4, Hs=Ws=256, C=128, n_heads=4, head_dim=32)
#define HW 65536          // Hs*Ws positions per batch
#define CH 128
#define NHEADS 4
#define HDIM 32
#define EPS 1e-5f
#define INV_NP (1.0f / 65536.0f)
#define INV_C (1.0f / 128.0f)

typedef float v4f __attribute__((ext_vector_type(4)));
typedef short v8s __attribute__((ext_vector_type(8)));
typedef unsigned int v4u __attribute__((ext_vector_type(4)));

__device__ __forceinline__ ushort f2bf(float f) {
    uint u = __float_as_uint(f);
    return (ushort)((u + 0x7FFFu + ((u >> 16) & 1u)) >> 16);
}

// HW packed f32->bf16 (RTNE), 2 elements / instruction
__device__ __forceinline__ uint cvtpk(float lo, float hi) {
    uint r;
    asm("v_cvt_pk_bf16_f32 %0, %1, %2" : "=v"(r) : "v"(lo), "v"(hi));
    return r;
}

__device__ __forceinline__ v8s pack8(const float4& a, const float4& b) {
    union { uint u[4]; v8s s; } r;
    r.u[0] = cvtpk(a.x, a.y);
    r.u[1] = cvtpk(a.z, a.w);
    r.u[2] = cvtpk(b.x, b.y);
    r.u[3] = cvtpk(b.z, b.w);
    return r.s;
}

// DPP butterfly add-reduce across the 16 lanes of a DPP row (ln = lane&15).
template<int CTRL>
__device__ __forceinline__ float dppadd(float x) {
    return x + __int_as_float(
        __builtin_amdgcn_mov_dpp(__float_as_int(x), CTRL, 0xF, 0xF, true));
}
__device__ __forceinline__ float red16(float x) {
    x = dppadd<0xB1>(x);    // quad_perm [1,0,3,2]  (xor 1)
    x = dppadd<0x4E>(x);    // quad_perm [2,3,0,1]  (xor 2)
    x = dppadd<0x141>(x);   // row_half_mirror      (combine quads)
    x = dppadd<0x140>(x);   // row_mirror           (combine halves)
    return x;
}

#define MFMA(a, b, c) __builtin_amdgcn_mfma_f32_16x16x32_bf16((a), (b), (c), 0, 0, 0)

// ---------------------------------------------------------------------------
// prep: build the FRAGMENT-ORDERED bf16 image of Wk,Wv (SWfrag) so kv_kernel
// waves load their resident B-fragments with 8 perfectly-coalesced dwordx4
// loads; zero the kv accumulator.
// SWfrag layout: frag f = w*8 + ks*2 + ct  (w=wave role 0..7, ks=0..3, ct=0..1)
//   SWfrag[f*512 + lane*8 + j] = W_t[c][col],
//   t = w>>2 (0:k, 1:v), col = (w&3)*32 + ct*16 + (lane&15),
//   c = ks*32 + (lane>>4)*8 + j.
// grid = 32, block = 256.
// ---------------------------------------------------------------------------
__global__ __launch_bounds__(256) void prep_kernel(const float* __restrict__ Wk,
                                                   const float* __restrict__ Wv,
                                                   ushort* __restrict__ SWfrag,
                                                   float* __restrict__ kv_g) {
    const int t = blockIdx.x * 256 + threadIdx.x;   // 0..8191
    kv_g[t] = 0.f;
    kv_g[t + 8192] = 0.f;
#pragma unroll
    for (int i = 0; i < 4; ++i) {
        const int o = i * 8192 + t;          // 0..32767
        const int f = o >> 9;
        const int lane = (o >> 3) & 63;
        const int j = o & 7;
        const int w = f >> 3;
        const int ks = (f >> 1) & 3;
        const int ct = f & 1;
        const int col = (w & 3) * 32 + ct * 16 + (lane & 15);
        const int c = ks * 32 + (lane >> 4) * 8 + j;
        const float s = (w < 4 ? Wk : Wv)[c * CH + col];
        SWfrag[o] = f2bf(s);
    }
}

// ---------------------------------------------------------------------------
// Kernel 1 (kv): column-split waves, W in REGISTERS.
// 512 threads = 8 waves; wave w owns 32 output channels of k (w<4) or v (w>=4)
// -> its 8 B-fragments (32 VGPR) loaded once per block. X staged per 32-pos
// tile into a double-buffered swizzled bf16 LDS image (conflict-free), each
// wave reads A-fragments for all 32 positions (8 ds_read_b128/tile). LN stats:
// in-lane ct-sum -> DPP red16 -> LDS quarter-exchange. Normalized k,v staged
// transposed (rotated) for per-head outer-product MFMA. 2 barriers/tile.
// LDS: Xbuf0 @0, Xbuf1 @4096, kst @8192, vst @12288, stats @16384 (ushort idx)
//      = 34 KB. grid = 512 (128/batch, 512 pos each), block = 512.
// ---------------------------------------------------------------------------
__global__ __launch_bounds__(512, 4) void kv_kernel(const float* __restrict__ X,
                                                    const ushort* __restrict__ SWfrag,
                                                    const float* __restrict__ gamma,
                                                    const float* __restrict__ beta,
                                                    float* __restrict__ kv_g) {
    __shared__ ushort lds[17408];          // 34816 B
    const int tid  = threadIdx.x;
    const int lane = tid & 63;
    const int w    = tid >> 6;             // 0..7
    const int q    = lane >> 4;
    const int ln   = lane & 15;

    const int batch  = blockIdx.x >> 7;
    const int blocal = blockIdx.x & 127;
    const float* Xb = X + ((size_t)batch * HW + (size_t)blocal * 512) * CH;

    // ---- resident B-fragments: 8 x 16B coalesced global loads ----
    v8s Bf[4][2];
#pragma unroll
    for (int ks = 0; ks < 4; ++ks)
#pragma unroll
        for (int ct = 0; ct < 2; ++ct)
            Bf[ks][ct] = *(const v8s*)(SWfrag + ((w * 8 + ks * 2 + ct) * 512 + lane * 8));

    const int cb = (w & 3) * 32;           // wave's channel base (within tensor)
    float g2[2], be2[2];
#pragma unroll
    for (int ct = 0; ct < 2; ++ct) {
        g2[ct]  = gamma[cb + ct * 16 + ln];
        be2[ct] = beta[cb + ct * 16 + ln];
    }

    // ---- loop-invariant addressing (ushort units) ----
    const int jrow = tid >> 4;             // staged row 0..31
    const int qt   = tid & 15;             // k-group 0..15
    const float* xptr = Xb + jrow * CH + qt * 8;
    const int sdst = jrow * 128 + ((qt + jrow) & 15) * 8;     // X-stage dest
    int aoff[4];                                              // A-read ks slots
#pragma unroll
    for (int ks = 0; ks < 4; ++ks) aoff[ks] = ((ks * 4 + q + ln) & 15) * 8;
    const int rowb0 = ln * 128;
    const int rowb1 = (16 + ln) * 128;
    const int tbase = (w < 4) ? 8192 : 12288;                 // kst or vst
    int soff[2][2];                                           // stage-write [ct][rt]
#pragma unroll
    for (int ct = 0; ct < 2; ++ct)
#pragma unroll
        for (int rt = 0; rt < 2; ++rt) {
            const int chn  = cb + ct * 16 + ln;
            const int slot = (rt * 2 + (q >> 1) + chn) & 3;
            soff[ct][rt] = tbase + chn * 32 + slot * 8 + (q & 1) * 4;
        }
    const int h  = w >> 1;                 // head for the outer product
    const int eh = w & 1;                  // e-half
    const int sl = (q + ln) & 3;
    const int koff0 = 8192  + (h * 32 + ln) * 32 + sl * 8;
    const int koff1 = 8192  + (h * 32 + 16 + ln) * 32 + sl * 8;
    const int voff  = 12288 + (h * 32 + eh * 16 + ln) * 32 + sl * 8;
    float* S = (float*)(lds + 16384);      // stats: [tensor][pos][quarter][s,sq]
    const int tens = w >> 2;

    v4f kv0 = {0.f, 0.f, 0.f, 0.f}, kv1 = kv0;

    // ---- prologue: stage tile 0 ----
    float4 xa0 = *(const float4*)xptr;
    float4 xa1 = *(const float4*)(xptr + 4);
    *(v8s*)(lds + sdst) = pack8(xa0, xa1);
    __syncthreads();

    for (int t = 0; t < 16; ++t) {
        // prefetch next tile's X (consumed after B2; latency hides under GEMM)
        if (t < 15) {
            const float* xp = xptr + (size_t)(t + 1) * 32 * CH;
            xa0 = *(const float4*)xp;
            xa1 = *(const float4*)(xp + 4);
        }
        const int cur = (t & 1) * 4096;

        // ---- GEMM: 32 pos x this wave's 32 channels ----
        v4f acc[2][2];
#pragma unroll
        for (int rt = 0; rt < 2; ++rt)
#pragma unroll
            for (int ct = 0; ct < 2; ++ct) acc[rt][ct] = (v4f){0.f, 0.f, 0.f, 0.f};
#pragma unroll
        for (int ks = 0; ks < 4; ++ks) {
            const v8s A0 = *(const v8s*)(lds + cur + rowb0 + aoff[ks]);
            const v8s A1 = *(const v8s*)(lds + cur + rowb1 + aoff[ks]);
            acc[0][0] = MFMA(A0, Bf[ks][0], acc[0][0]);
            acc[0][1] = MFMA(A0, Bf[ks][1], acc[0][1]);
            acc[1][0] = MFMA(A1, Bf[ks][0], acc[1][0]);
            acc[1][1] = MFMA(A1, Bf[ks][1], acc[1][1]);
        }

        // ---- LN stats: quarter-partials via DPP, exchange via LDS ----
#pragma unroll
        for (int rt = 0; rt < 2; ++rt)
#pragma unroll
            for (int r = 0; r < 4; ++r) {
                float s  = acc[rt][0][r] + acc[rt][1][r];
                float sq = fmaf(acc[rt][0][r], acc[rt][0][r],
                                acc[rt][1][r] * acc[rt][1][r]);
                s  = red16(s);
                sq = red16(sq);
                if (ln == 0) {
                    const int pos = rt * 16 + q * 4 + r;
                    *(float2*)(S + (tens * 32 + pos) * 8 + (w & 3) * 2) =
                        make_float2(s, sq);
                }
            }
        __syncthreads();   // B2: stats ready; prev-tile A-reads done everywhere

        // write next X tile into the other buffer (read was 2 barriers ago)
        if (t < 15) *(v8s*)(lds + (cur ^ 4096) + sdst) = pack8(xa0, xa1);

        // combine quarters -> mu, rsqrt
        float mr[2][4], rs[2][4];
#pragma unroll
        for (int rt = 0; rt < 2; ++rt)
#pragma unroll
            for (int r = 0; r < 4; ++r) {
                const int pos = rt * 16 + q * 4 + r;
                const float4 f0 = *(const float4*)(S + (tens * 32 + pos) * 8);
                const float4 f1 = *(const float4*)(S + (tens * 32 + pos) * 8 + 4);
                const float s  = f0.x + f0.z + f1.x + f1.z;
                const float sq = f0.y + f0.w + f1.y + f1.w;
                const float mu = s * INV_C;
                const float rv = __builtin_amdgcn_rsqf(fmaf(sq, INV_C, -mu * mu) + EPS);
                rs[rt][r] = rv;
                mr[rt][r] = mu * rv;
            }

        // ---- normalize + stage transposed (rotated, conflict-free b64) ----
#pragma unroll
        for (int ct = 0; ct < 2; ++ct)
#pragma unroll
            for (int rt = 0; rt < 2; ++rt) {
                const float n0 = fmaf(fmaf(acc[rt][ct][0], rs[rt][0], -mr[rt][0]), g2[ct], be2[ct]);
                const float n1 = fmaf(fmaf(acc[rt][ct][1], rs[rt][1], -mr[rt][1]), g2[ct], be2[ct]);
                const float n2 = fmaf(fmaf(acc[rt][ct][2], rs[rt][2], -mr[rt][2]), g2[ct], be2[ct]);
                const float n3 = fmaf(fmaf(acc[rt][ct][3], rs[rt][3], -mr[rt][3]), g2[ct], be2[ct]);
                uint2 u;
                u.x = cvtpk(n0, n1);
                u.y = cvtpk(n2, n3);
                *(uint2*)(lds + soff[ct][rt]) = u;
            }
        __syncthreads();   // B3: kst/vst ready

        // ---- per-head outer product: kv[h] += k_norm^T * v_norm ----
        {
            const v8s Ad0 = *(const v8s*)(lds + koff0);
            const v8s Ad1 = *(const v8s*)(lds + koff1);
            const v8s Be  = *(const v8s*)(lds + voff);
            kv0 = MFMA(Ad0, Be, kv0);
            kv1 = MFMA(Ad1, Be, kv1);
        }
    }

    float* dst = kv_g + (batch * NHEADS + h) * (HDIM * HDIM);
#pragma unroll
    for (int db = 0; db < 2; ++db) {
        const v4f f = db == 0 ? kv0 : kv1;
#pragma unroll
        for (int r = 0; r < 4; ++r) {
            const int d = db * 16 + q * 4 + r;
            const int e = eh * 16 + ln;
            atomicAdd(&dst[d * HDIM + e], f[r]);
        }
    }
}

// ---------------------------------------------------------------------------
// Kernel 2: SWeffT = swizzled bf16 image of Weff^T where
// Weff[c][o] = (1/NP) sum_d Wq[c][h][d] kv[b][h][d][e], o = e*4+h.
// grid 64, block 256.
// ---------------------------------------------------------------------------
__global__ __launch_bounds__(256) void weff_kernel(const float* __restrict__ Wq,
                                                   const float* __restrict__ kv_g,
                                                   ushort* __restrict__ SWeffT) {
    const int b = blockIdx.x >> 4;
    const int part = blockIdx.x & 15;
    const int base = part * 1024 + threadIdx.x * 4;
    const int c = base >> 7;
    const int o0 = base & 127;
    const float* kvb = kv_g + b * (NHEADS * HDIM * HDIM);
#pragma unroll
    for (int n = 0; n < 4; ++n) {
        const int o = o0 + n;
        const int h = o & 3;
        const int e = o >> 2;
        float s = 0.f;
#pragma unroll
        for (int d = 0; d < HDIM; ++d)
            s += Wq[c * CH + h * HDIM + d] * kvb[h * (HDIM * HDIM) + d * HDIM + e];
        SWeffT[b * (CH * CH) + o * 128 + (((c >> 3) + o) & 15) * 8 + (c & 7)] = f2bf(s * INV_NP);
    }
}

// ---------------------------------------------------------------------------
// Kernel 3 (out): operand-swapped MFMA — A = Weff rows (from the swizzled
// LDS image), B = X positions. C rows = output channels -> float4 stores.
// Each wave owns disjoint 16 positions, prefetched.
// grid = 1024 (256/batch, 4 tiles of 64 pos each), block = 256.
// ---------------------------------------------------------------------------
__global__ __launch_bounds__(256, 4) void out_kernel(const float* __restrict__ X,
                                                     const ushort* __restrict__ SWeffT,
                                                     float* __restrict__ out) {
    __shared__ ushort lds[16384];
    const int tid  = threadIdx.x;
    const int lane = tid & 63;
    const int w    = tid >> 6;
    const int q    = lane >> 4;
    const int ln   = lane & 15;

    const int batch  = blockIdx.x >> 8;
    const int blocal = blockIdx.x & 255;
    const size_t p0 = (size_t)batch * HW + (size_t)blocal * 256;

    {
        const v4u* s = (const v4u*)(SWeffT + batch * (CH * CH));
        v4u* d = (v4u*)lds;
#pragma unroll
        for (int n = 0; n < 8; ++n) d[n * 256 + tid] = s[n * 256 + tid];
    }

    int arow[8];
#pragma unroll
    for (int ot = 0; ot < 8; ++ot) arow[ot] = (ot * 16 + ln) * 128;
    int aks[4];
#pragma unroll
    for (int ks = 0; ks < 4; ++ks) aks[ks] = ((ks * 4 + q + ln) & 15) * 8;

    const float* xbase = X + (p0 + w * 16 + ln) * CH + q * 8;
    float* obase       = out + (p0 + w * 16 + ln) * CH + q * 4;

    float4 xa[8];
#pragma unroll
    for (int ks = 0; ks < 4; ++ks) {
        xa[2 * ks]     = *(const float4*)(xbase + ks * 32);
        xa[2 * ks + 1] = *(const float4*)(xbase + ks * 32 + 4);
    }
    __syncthreads();

    v8s Bx[4];
#pragma unroll
    for (int ks = 0; ks < 4; ++ks) Bx[ks] = pack8(xa[2 * ks], xa[2 * ks + 1]);

    for (int t = 0; t < 4; ++t) {
        if (t < 3) {
            const float* xp = xbase + (size_t)(t + 1) * 64 * CH;
#pragma unroll
            for (int ks = 0; ks < 4; ++ks) {
                xa[2 * ks]     = *(const float4*)(xp + ks * 32);
                xa[2 * ks + 1] = *(const float4*)(xp + ks * 32 + 4);
            }
        }

        v4f acc[8];
#pragma unroll
        for (int ot = 0; ot < 8; ++ot) acc[ot] = (v4f){0.f, 0.f, 0.f, 0.f};
#pragma unroll
        for (int ks = 0; ks < 4; ++ks) {
#pragma unroll
            for (int ot = 0; ot < 8; ++ot) {
                const v8s Aw = *(const v8s*)(lds + arow[ot] + aks[ks]);
                acc[ot] = MFMA(Aw, Bx[ks], acc[ot]);
            }
        }

        float* op = obase + (size_t)t * 64 * CH;
#pragma unroll
        for (int ot = 0; ot < 8; ++ot) {
            float4 s;
            s.x = acc[ot][0]; s.y = acc[ot][1]; s.z = acc[ot][2]; s.w = acc[ot][3];
            *(float4*)(op + ot * 16) = s;
        }

        if (t < 3) {
#pragma unroll
            for (int ks = 0; ks < 4; ++ks) Bx[ks] = pack8(xa[2 * ks], xa[2 * ks + 1]);
        }
    }
}

extern "C" void kernel_launch(void* const* d_in, const int* in_sizes, int n_in,
                              void* d_out, int out_size, void* d_ws, size_t ws_size,
                              hipStream_t stream) {
    const float* X     = (const float*)d_in[0];
    const float* Wq    = (const float*)d_in[1];
    const float* Wk    = (const float*)d_in[2];
    const float* Wv    = (const float*)d_in[3];
    const float* gamma = (const float*)d_in[4];
    const float* beta  = (const float*)d_in[5];
    float* out = (float*)d_out;

    float*  kv_g   = (float*)d_ws;                       // 64 KB
    ushort* SWfrag = (ushort*)((char*)d_ws + 65536);     // 64 KB
    ushort* SWeffT = (ushort*)((char*)d_ws + 131072);    // 128 KB

    prep_kernel<<<32, 256, 0, stream>>>(Wk, Wv, SWfrag, kv_g);
    kv_kernel<<<512, 512, 0, stream>>>(X, SWfrag, gamma, beta, kv_g);
    weff_kernel<<<64, 256, 0, stream>>>(Wq, kv_g, SWeffT);
    out_kernel<<<1024, 256, 0, stream>>>(X, SWeffT, out);
}